// Round 12
// baseline (106.670 us; speedup 1.0000x reference)
//
#include <hip/hip_runtime.h>

typedef __attribute__((ext_vector_type(4))) float f32x4;
typedef __attribute__((ext_vector_type(8))) _Float16 f16x8;

#define D_ 64
#define K_ 512
#define REP 9   // DIAGNOSTIC: amplify main loop so vq enters rocprof top-5.
                // Output identical every rep -> correctness unchanged.

// 2-limb f16: a = hi + lo (22 mantissa bits), limbs K-concatenated.
// Frag layout (identical builder for codebook and queries => within-K-block
// permutation cancels). Queries NEGATED at staging; acc seeded with 0.5||e||^2
// via MFMA C-operand: score = 0.5||e||^2 - c.e (lo.lo dropped, ~1.5e-5).
// Structure: grid 256 x 512 thr (8 waves), Q=256/block, single-phase staging,
// wave w owns entries 64w..64w+63 in registers, qt sweep barrier-free.
__global__ __launch_bounds__(512, 1)
void vq_fused(const float* __restrict__ codes,
              const float* __restrict__ codebook,
              float* __restrict__ out) {
  __shared__ _Float16 Af[256 * 128];     // 64 KB query frags
  __shared__ float esq_s[K_];            // 2 KB
  __shared__ float smin[8][256];         // 8 KB
  __shared__ int   simin[8][256];        // 8 KB
  __shared__ int   best[256];            // 1 KB

  const int t = threadIdx.x;
  const int w = t >> 6, l = t & 63, lh = l >> 4, ll = l & 15;
  const long long qb = (long long)blockIdx.x * 256;

  // ---- issue all query loads first (HBM latency hides under ef build) ----
  const int aq = (w & 3) * 64 + l;
  const int dhalf = (w >> 2) * 32;
  const float* asrc = codes + (qb + aq) * D_ + dhalf;
  f32x4 av[8];
#pragma unroll
  for (int j = 0; j < 8; ++j) av[j] = *(const f32x4*)(asrc + 4 * j);

  // ---- build ef frags + 0.5||e||^2 in-register (once per block) ----
  f16x8 ef[4][4];
#pragma unroll
  for (int i = 0; i < 4; ++i) {
    const int e = (w * 4 + i) * 16 + ll;
    const float* src = codebook + e * D_ + lh * 4;
    _Float16 hi[4][4], lo[4][4];
    float es = 0.f;
#pragma unroll
    for (int j = 0; j < 4; ++j) {
      f32x4 v = *(const f32x4*)(src + 16 * j);
#pragma unroll
      for (int si = 0; si < 4; ++si) {
        float a = v[si];
        es += a * a;
        _Float16 h = (_Float16)a;
        hi[j][si] = h;
        lo[j][si] = (_Float16)(a - (float)h);
      }
    }
    es += __shfl_xor(es, 16, 64);
    es += __shfl_xor(es, 32, 64);
    if (lh == 0) esq_s[e] = 0.5f * es;
#pragma unroll
    for (int s = 0; s < 8; ++s) {
      ef[i][0][s] = hi[s >> 2][s & 3];          // dims 0..31  hi
      ef[i][1][s] = hi[2 + (s >> 2)][s & 3];    // dims 32..63 hi
      ef[i][2][s] = lo[s >> 2][s & 3];          // dims 0..31  lo
      ef[i][3][s] = lo[2 + (s >> 2)][s & 3];    // dims 32..63 lo
    }
  }

  // ---- stage queries: negated 2-limb frags ----
  {
    const int kb = dhalf >> 5;
    _Float16* base = Af + (aq >> 4) * 2048 + kb * 512 + (aq & 15) * 8;
#pragma unroll
    for (int pp = 0; pp < 4; ++pp) {
      f16x8 wh, wl;
#pragma unroll
      for (int si = 0; si < 4; ++si) {
        float a0 = -av[pp][si];
        _Float16 h0 = (_Float16)a0;
        wh[si] = h0; wl[si] = (_Float16)(a0 - (float)h0);
        float a1 = -av[pp + 4][si];
        _Float16 h1 = (_Float16)a1;
        wh[4 + si] = h1; wl[4 + si] = (_Float16)(a1 - (float)h1);
      }
      *(f16x8*)(base + pp * 128) = wh;
      *(f16x8*)(base + 1024 + pp * 128) = wl;
    }
  }
  __syncthreads();                              // barrier #1: Af + esq_s ready

  f32x4 esqr[4];
#pragma unroll
  for (int i = 0; i < 4; ++i)
    esqr[i] = *(const f32x4*)(esq_s + (w * 4 + i) * 16 + lh * 4);

  // ---- main loop, amplified REP x (diagnostic; results identical each rep) ----
#pragma unroll 1
  for (int rep = 0; rep < REP; ++rep) {
    int zoff = 0;
    asm volatile("" : "+v"(zoff));              // opaque 0: defeats CSE across reps
#pragma unroll 2
    for (int qt = 0; qt < 16; ++qt) {
      f16x8 qf[4];
#pragma unroll
      for (int kb = 0; kb < 4; ++kb)
        qf[kb] = *(const f16x8*)(&Af[qt * 2048 + kb * 512 + l * 8 + zoff]);
      float mv = 3.4e38f; int mi = 0;
#pragma unroll
      for (int i = 0; i < 4; ++i) {
        f32x4 a = esqr[i];
        a = __builtin_amdgcn_mfma_f32_16x16x32_f16(ef[i][0], qf[0], a, 0, 0, 0);
        a = __builtin_amdgcn_mfma_f32_16x16x32_f16(ef[i][1], qf[1], a, 0, 0, 0);
        a = __builtin_amdgcn_mfma_f32_16x16x32_f16(ef[i][2], qf[0], a, 0, 0, 0);
        a = __builtin_amdgcn_mfma_f32_16x16x32_f16(ef[i][3], qf[1], a, 0, 0, 0);
        a = __builtin_amdgcn_mfma_f32_16x16x32_f16(ef[i][0], qf[2], a, 0, 0, 0);
        a = __builtin_amdgcn_mfma_f32_16x16x32_f16(ef[i][1], qf[3], a, 0, 0, 0);
#pragma unroll
        for (int r = 0; r < 4; ++r) {
          const int e = (w * 4 + i) * 16 + lh * 4 + r;
          if (a[r] < mv) { mv = a[r]; mi = e; }
        }
      }
#pragma unroll
      for (int off = 16; off <= 32; off <<= 1) {
        float ov = __shfl_xor(mv, off, 64);
        int oi = __shfl_xor(mi, off, 64);
        if (ov < mv || (ov == mv && oi < mi)) { mv = ov; mi = oi; }
      }
      if (l < 16) {
        smin[w][qt * 16 + ll] = mv;
        simin[w][qt * 16 + ll] = mi;
      }
    }
  }
  __syncthreads();                              // barrier #2: all smin written

  // ---- combine 8 waves (disjoint ascending entry ranges; tie -> lower index) ----
  if (t < 256) {
    float bv = smin[0][t]; int bi = simin[0][t];
#pragma unroll
    for (int ww = 1; ww < 8; ++ww) {
      float v = smin[ww][t]; int ii = simin[ww][t];
      if (v < bv || (v == bv && ii < bi)) { bv = v; bi = ii; }
    }
    best[t] = bi;
  }
  __syncthreads();

  // ---- gather: exact fp32 rows from global codebook (L2-hot) ----
#pragma unroll
  for (int i2 = 0; i2 < 8; ++i2) {
    const int f = t + 512 * i2;
    const int q = f >> 4, g = f & 15;
    const int e = best[q];
    f32x4 v = *(const f32x4*)(codebook + e * D_ + g * 4);
    *(f32x4*)(out + (qb + q) * D_ + g * 4) = v;
  }
}

extern "C" void kernel_launch(void* const* d_in, const int* in_sizes, int n_in,
                              void* d_out, int out_size, void* d_ws, size_t ws_size,
                              hipStream_t stream) {
  const float* codes = (const float*)d_in[0];
  const float* codebook = (const float*)d_in[1];
  float* out = (float*)d_out;
  const int Q = in_sizes[0] / D_;        // 65536
  const int grid = Q / 256;              // 256
  vq_fused<<<grid, 512, 0, stream>>>(codes, codebook, out);
}

// Round 13
// 25.775 us; speedup vs baseline: 4.1385x; 4.1385x over previous
//
#include <hip/hip_runtime.h>

typedef __attribute__((ext_vector_type(4))) float f32x4;
typedef __attribute__((ext_vector_type(8))) _Float16 f16x8;
typedef __attribute__((ext_vector_type(4))) _Float16 f16x4;

#define D_ 64
#define K_ 512

// 2-limb f16: a = hi + lo (22 mantissa bits), limbs K-concatenated (128 k's).
// Frag layout (IDENTICAL builder for codebook and queries => any within-K-block
// lane permutation cancels in A.B): half-off = tile*2048 + kb*512 + lh*128 +
// ll*8 + j*4 + si, dim-within-kb = lh*4 + 16j + si. Queries NEGATED at staging;
// acc seeded with 0.5||e||^2 via MFMA C-operand: score = 0.5||e||^2 - c.e
// (lo.lo dropped, ~1.5e-5 error; absmax 0.0 across rounds 5-12).
//
// Structure: grid 256 x 1024 thr (16 waves, 4/SIMD), Q=256/block. Single-phase
// staging (64 KB Af), then barrier-free qt sweep: wave w owns entries
// 32w..32w+31 in registers. 4 waves/SIMD cross-hide MFMA-chain + argmin-chain
// latency (round-12 diagnosis: MfmaUtil 41% at 2 waves/SIMD = interleave gap).
__global__ __launch_bounds__(1024, 4)
void vq_fused(const float* __restrict__ codes,
              const float* __restrict__ codebook,
              float* __restrict__ out) {
  __shared__ _Float16 Af[256 * 128];     // 64 KB query frags
  __shared__ float esq_s[K_];            // 2 KB
  __shared__ float smin[16][256];        // 16 KB
  __shared__ int   simin[16][256];       // 16 KB
  __shared__ int   best[256];            // 1 KB

  const int t = threadIdx.x;
  const int w = t >> 6, l = t & 63, lh = l >> 4, ll = l & 15;
  const long long qb = (long long)blockIdx.x * 256;

  // ---- issue all query loads first (HBM latency hides under ef build) ----
  // thread covers query aq = t>>2, dims dq*16..dq*16+15 (fully coalesced)
  const int aq = t >> 2, dq = t & 3;
  const float* asrc = codes + (qb + aq) * D_ + dq * 16;
  f32x4 av[4];
#pragma unroll
  for (int g = 0; g < 4; ++g) av[g] = *(const f32x4*)(asrc + 4 * g);

  // ---- build ef frags + 0.5||e||^2 in-register (wave owns entries 32w..32w+31) ----
  f16x8 ef[2][4];
#pragma unroll
  for (int i = 0; i < 2; ++i) {
    const int e = (w * 2 + i) * 16 + ll;
    const float* src = codebook + e * D_ + lh * 4;
    _Float16 hi[4][4], lo[4][4];
    float es = 0.f;
#pragma unroll
    for (int j = 0; j < 4; ++j) {
      f32x4 v = *(const f32x4*)(src + 16 * j);
#pragma unroll
      for (int si = 0; si < 4; ++si) {
        float a = v[si];
        es += a * a;
        _Float16 h = (_Float16)a;
        hi[j][si] = h;
        lo[j][si] = (_Float16)(a - (float)h);
      }
    }
    es += __shfl_xor(es, 16, 64);         // sum the 4 lh groups
    es += __shfl_xor(es, 32, 64);
    if (lh == 0) esq_s[e] = 0.5f * es;
#pragma unroll
    for (int s = 0; s < 8; ++s) {
      ef[i][0][s] = hi[s >> 2][s & 3];          // dims 0..31  hi
      ef[i][1][s] = hi[2 + (s >> 2)][s & 3];    // dims 32..63 hi
      ef[i][2][s] = lo[s >> 2][s & 3];          // dims 0..31  lo
      ef[i][3][s] = lo[2 + (s >> 2)][s & 3];    // dims 32..63 lo
    }
  }

  // ---- stage queries: negated 2-limb frags (8 x ds_write_b64 per thread) ----
  {
    const int kb = dq >> 1, j = dq & 1;         // dims = kb*32 + j*16 + (pp*4+si)
    _Float16* base = Af + (aq >> 4) * 2048 + kb * 512 + (aq & 15) * 8 + j * 4;
#pragma unroll
    for (int pp = 0; pp < 4; ++pp) {            // pp = lh group
      f16x4 wh, wl;
#pragma unroll
      for (int si = 0; si < 4; ++si) {
        float na = -av[pp][si];                 // negate query
        _Float16 h = (_Float16)na;
        wh[si] = h;
        wl[si] = (_Float16)(na - (float)h);
      }
      *(f16x4*)(base + pp * 128) = wh;          // hi limb: kb
      *(f16x4*)(base + 1024 + pp * 128) = wl;   // lo limb: kb+2
    }
  }
  __syncthreads();                              // barrier #1: Af + esq_s ready

  // per-lane 0.5||e||^2 for C/D rows: entries (w*2+i)*16 + lh*4 + r
  f32x4 esqr[2];
#pragma unroll
  for (int i = 0; i < 2; ++i)
    esqr[i] = *(const f32x4*)(esq_s + (w * 2 + i) * 16 + lh * 4);

  // ---- main loop: 16 q-tiles, barrier-free ----
#pragma unroll 2
  for (int qt = 0; qt < 16; ++qt) {
    f16x8 qf[4];
#pragma unroll
    for (int kb = 0; kb < 4; ++kb)
      qf[kb] = *(const f16x8*)(&Af[qt * 2048 + kb * 512 + l * 8]);

    // two independent MFMA chains + two independent argmin chains (ILP)
    f32x4 a0 = esqr[0], a1 = esqr[1];
    a0 = __builtin_amdgcn_mfma_f32_16x16x32_f16(ef[0][0], qf[0], a0, 0, 0, 0);
    a1 = __builtin_amdgcn_mfma_f32_16x16x32_f16(ef[1][0], qf[0], a1, 0, 0, 0);
    a0 = __builtin_amdgcn_mfma_f32_16x16x32_f16(ef[0][1], qf[1], a0, 0, 0, 0);
    a1 = __builtin_amdgcn_mfma_f32_16x16x32_f16(ef[1][1], qf[1], a1, 0, 0, 0);
    a0 = __builtin_amdgcn_mfma_f32_16x16x32_f16(ef[0][2], qf[0], a0, 0, 0, 0);
    a1 = __builtin_amdgcn_mfma_f32_16x16x32_f16(ef[1][2], qf[0], a1, 0, 0, 0);
    a0 = __builtin_amdgcn_mfma_f32_16x16x32_f16(ef[0][3], qf[1], a0, 0, 0, 0);
    a1 = __builtin_amdgcn_mfma_f32_16x16x32_f16(ef[1][3], qf[1], a1, 0, 0, 0);
    a0 = __builtin_amdgcn_mfma_f32_16x16x32_f16(ef[0][0], qf[2], a0, 0, 0, 0);
    a1 = __builtin_amdgcn_mfma_f32_16x16x32_f16(ef[1][0], qf[2], a1, 0, 0, 0);
    a0 = __builtin_amdgcn_mfma_f32_16x16x32_f16(ef[0][1], qf[3], a0, 0, 0, 0);
    a1 = __builtin_amdgcn_mfma_f32_16x16x32_f16(ef[1][1], qf[3], a1, 0, 0, 0);

    float mv0 = a0[0]; int mi0 = (w * 2) * 16 + lh * 4;
    float mv1 = a1[0]; int mi1 = (w * 2 + 1) * 16 + lh * 4;
#pragma unroll
    for (int r = 1; r < 4; ++r) {
      const int e0 = (w * 2) * 16 + lh * 4 + r;
      if (a0[r] < mv0) { mv0 = a0[r]; mi0 = e0; }
      const int e1 = (w * 2 + 1) * 16 + lh * 4 + r;
      if (a1[r] < mv1) { mv1 = a1[r]; mi1 = e1; }
    }
    // combine (i=1 entries are strictly larger indices: strict < keeps first-min)
    float mv = mv0; int mi = mi0;
    if (mv1 < mv0) { mv = mv1; mi = mi1; }

    // reduce over the 4 lh groups (same query col, different entries)
#pragma unroll
    for (int off = 16; off <= 32; off <<= 1) {
      float ov = __shfl_xor(mv, off, 64);
      int oi = __shfl_xor(mi, off, 64);
      if (ov < mv || (ov == mv && oi < mi)) { mv = ov; mi = oi; }
    }
    if (l < 16) {
      smin[w][qt * 16 + ll] = mv;
      simin[w][qt * 16 + ll] = mi;
    }
  }
  __syncthreads();                              // barrier #2: all smin written

  // ---- combine 16 waves (disjoint ascending entry ranges; tie -> lower index) ----
  if (t < 256) {
    float bv = smin[0][t]; int bi = simin[0][t];
#pragma unroll
    for (int ww = 1; ww < 16; ++ww) {
      float v = smin[ww][t]; int ii = simin[ww][t];
      if (v < bv || (v == bv && ii < bi)) { bv = v; bi = ii; }
    }
    best[t] = bi;
  }
  __syncthreads();

  // ---- gather: exact fp32 rows from global codebook (L2-hot) ----
#pragma unroll
  for (int i2 = 0; i2 < 4; ++i2) {
    const int f = t + 1024 * i2;                // 4096 f32x4 per block
    const int q = f >> 4, g = f & 15;
    const int e = best[q];
    f32x4 v = *(const f32x4*)(codebook + e * D_ + g * 4);
    *(f32x4*)(out + (qb + q) * D_ + g * 4) = v;
  }
}

extern "C" void kernel_launch(void* const* d_in, const int* in_sizes, int n_in,
                              void* d_out, int out_size, void* d_ws, size_t ws_size,
                              hipStream_t stream) {
  const float* codes = (const float*)d_in[0];
  const float* codebook = (const float*)d_in[1];
  float* out = (float*)d_out;
  const int Q = in_sizes[0] / D_;        // 65536
  const int grid = Q / 256;              // 256
  vq_fused<<<grid, 1024, 0, stream>>>(codes, codebook, out);
}